// Round 10
// baseline (405.051 us; speedup 1.0000x reference)
//
#include <hip/hip_runtime.h>
#include <cstdint>
#include <cstddef>

// ---------------------------------------------------------------------------
// cross_attention: b=8, c=32, 252x252, ws=8 -> padded 256x256.
// tokens l=(i1,j1) in 32x32, features d'=(i0*256 + j0*32 + c) in 2048.
// Pipeline (R12, resubmitted): pack_qk_fused v4 — LDS-resident strip with
//   STATIC 136 KB tile. R7 evidence: two different deep-pipeline schemes
//   both plateau at 2.7-2.8 TB/s; dispatch traffic = 125R + 131W MB where
//   64 MB of W is the phase-C rescale rewrite. v4 stages the block's whole
//   1024x64 bf16 output in LDS (stride-68 rows), accumulates norms during
//   staging, then does ONE scaled write-out: ~191 MB total traffic (-25%).
//   -> pack_v (raw bf16 Vt + fused svsum atomics) -> S = Qh Kh^T * 2048^-0.5
//   -> softmax -> Ot = (rsqrt(svsum).*Vt) P^T fused scatter.
// Audits: LDS 141,568 B < 160 KB; all LDS/global indices bounds-checked;
// 8B-aligned uint2 paths; no raw barriers (plain __syncthreads only).
// ---------------------------------------------------------------------------

typedef __bf16 bf16x8 __attribute__((ext_vector_type(8)));
typedef float  f32x4  __attribute__((ext_vector_type(4)));

__device__ __forceinline__ unsigned int f2bf(float f) {
  unsigned int u = __builtin_bit_cast(unsigned int, f);
  u += 0x7FFFu + ((u >> 16) & 1u);   // round-to-nearest-even
  return u >> 16;
}
__device__ __forceinline__ float bf2f(unsigned int h) {
  return __builtin_bit_cast(float, h << 16);
}

__device__ __forceinline__ void load_lds16(const void* g, void* l) {
  __builtin_amdgcn_global_load_lds(
      (const __attribute__((address_space(1))) void*)g,
      (__attribute__((address_space(3))) void*)l, 16, 0, 0);
}

// ---------------------------------------------------------------------------
// Kernel 1 (v4, static LDS): fused norm+pack for Q,K, LDS-resident strip.
// Block = (t, b, i0, j0g): owns 32c x 32h x 64w = 1024 tokens x 64 d'.
// Phase A (stage): each thread reads 2 float4/row (channels c2, c2+16) for
//   32 rows — 64 independent global loads, no barriers — accumulates
//   weighted squares (reflect weights: 247..250 x2, >=252 -> 0) in fp32,
//   writes raw bf16 into tile[l*68 + o]  (o = j0l*32 + c; stride 68 keeps
//   ds_write_b16 at ~8-way worst and ds_read_b64 at ~4-way, 8B-aligned).
// Phase B: block reduce -> sclt[o] = 1/max(||.||,1e-12)  (norm from fp32
//   squares, same numerics as the passing v2/v3 scheme).
// Phase C' (write-out): thread (qd,lr) scales tile quads and stores uint2;
//   16 lanes cover 128B contiguous of each token row. Qh/Kh written ONCE.
// Tail (j0g==3, ch==15): loads mirrored values (w 252..255 <- 250..247),
//   weight 0; rows h>=252 mirrored via hs with row weight 0.
// ---------------------------------------------------------------------------
__global__ __launch_bounds__(256)
void pack_qk_fused(const float* __restrict__ q, const float* __restrict__ k,
                   unsigned short* __restrict__ Qh,
                   unsigned short* __restrict__ Kh) {
  int bx  = blockIdx.x;          // grid 512
  int t   = bx >> 8;             // 0..1
  int b   = (bx >> 5) & 7;
  int i0  = (bx >> 2) & 7;
  int j0g = bx & 3;
  const float* xb = (t ? k : q) + (size_t)b * 32 * 63504;

  __shared__ unsigned short tile[1024 * 68];   // 136 KB, static (m201 prec.)
  __shared__ float red[512];
  __shared__ float sclt[64];                   // [o = j0l*32 + c]

  int tid = threadIdx.x;
  int ch  = tid & 15;              // 16B chunk within 64-w slice
  int c2  = tid >> 4;              // c = c2, c2+16

  int wbase = j0g * 64 + ch * 4;
  float we[4];
  #pragma unroll
  for (int e = 0; e < 4; e++) {
    int w = wbase + e;
    we[e] = (w >= 252) ? 0.f : (((unsigned)(w - 247) <= 3u) ? 2.f : 1.f);
  }
  bool tail = (wbase == 252);      // only j0g==3, ch==15

  float pa = 0.f, pb = 0.f;        // window sums for c2 / c2+16 (j0l fixed)
  unsigned short* X = (t ? Kh : Qh) + (size_t)b * 1024 * 2048;

  int j0l  = ch >> 3;              // w-window within strip for this chunk
  int j1b  = (ch * 4) & 31;        // first token j1 of this chunk

  // ---- Phase A: stage + squares (no barriers; 64 independent loads) ----
  for (int i1 = 0; i1 < 32; i1++) {
    int h  = i0 * 32 + i1;
    int hs = (h < 252) ? h : 502 - h;
    float rw = (h >= 252) ? 0.f : (((unsigned)(h - 247) <= 3u) ? 2.f : 1.f);
    const float* rowp = xb + (size_t)hs * 252;
    int lbase = i1 * 32 + j1b;

    #pragma unroll
    for (int it = 0; it < 2; it++) {
      int c = c2 + it * 16;
      const float* src = rowp + (size_t)c * 63504;
      float4 vv;
      if (!tail) {
        vv = *(const float4*)&src[wbase];
      } else {  // w 252..255 mirror to 250,249,248,247
        vv.x = src[250]; vv.y = src[249]; vv.z = src[248]; vv.w = src[247];
      }
      float s = rw * (we[0] * vv.x * vv.x + we[1] * vv.y * vv.y +
                      we[2] * vv.z * vv.z + we[3] * vv.w * vv.w);
      if (it == 0) pa += s; else pb += s;
      int o = j0l * 32 + c;
      unsigned short* tp = &tile[(size_t)lbase * 68 + o];
      tp[0]   = (unsigned short)f2bf(vv.x);
      tp[68]  = (unsigned short)f2bf(vv.y);
      tp[136] = (unsigned short)f2bf(vv.z);
      tp[204] = (unsigned short)f2bf(vv.w);
    }
  }
  __syncthreads();

  // ---- Phase B: reduce partials -> 64 scales (indexed by o) ----
  red[tid] = pa; red[256 + tid] = pb;
  __syncthreads();
  if (tid < 64) {
    int c = tid & 31, jl = tid >> 5;
    int base = (c & 15) * 16 + jl * 8 + ((c >= 16) ? 256 : 0);
    float s = 0.f;
    #pragma unroll
    for (int u = 0; u < 8; u++) s += red[base + u];
    sclt[jl * 32 + c] = 1.f / fmaxf(sqrtf(s), 1e-12f);
  }
  __syncthreads();

  // ---- Phase C': scaled write-out, each output byte written once ----
  {
    int qd = tid & 15;             // o quad: o = qd*4 .. qd*4+3
    int lr = tid >> 4;             // token row group
    float sc[4];
    #pragma unroll
    for (int m = 0; m < 4; m++) sc[m] = sclt[qd * 4 + m];
    unsigned short* Xb = &X[i0 * 256 + j0g * 64 + qd * 4];
    #pragma unroll 4
    for (int it = 0; it < 64; it++) {
      int l = it * 16 + lr;
      uint2 u = *(const uint2*)&tile[(size_t)l * 68 + qd * 4];
      uint2 o2;
      o2.x = f2bf(bf2f(u.x & 0xFFFF) * sc[0]) |
             (f2bf(bf2f(u.x >> 16)   * sc[1]) << 16);
      o2.y = f2bf(bf2f(u.y & 0xFFFF) * sc[2]) |
             (f2bf(bf2f(u.y >> 16)   * sc[3]) << 16);
      *(uint2*)&Xb[(size_t)l * 2048] = o2;
    }
  }
}

// ---------------------------------------------------------------------------
// Kernel 2: pack V to bf16 Vt[d'][l] — RAW (scale folded into gemm2), no LDS.
// Fused: sum-of-squares per (b, d') row accumulated into svsum via 4-lane
// shfl reduce + one atomicAdd per (c, j0) per block. svsum zeroed via
// hipMemsetAsync before launch.
// ---------------------------------------------------------------------------
__global__ void pack_v_kernel(const float* __restrict__ v,
                              unsigned short* __restrict__ Vt,
                              float* __restrict__ svsum) {
  int bx = blockIdx.x;
  int b  = bx >> 8;
  int i0 = (bx >> 5) & 7;
  int i1 = bx & 31;
  int h  = i0 * 32 + i1;
  int hs = (h < 252) ? h : 502 - h;
  const float* src = v + (size_t)b * 32 * 63504 + (size_t)hs * 252;
  unsigned short* dst = Vt + (size_t)b * 2048 * 1024
                           + (size_t)(i0 * 256) * 1024 + i1 * 32;

  int tid = threadIdx.x;
  int j1c = tid & 3;
  int c   = (tid >> 2) & 31;
  int j0g = tid >> 7;          // 0..1
  const float* s = src + (size_t)c * 63504;

  float psum[4];

  #pragma unroll
  for (int jj = 0; jj < 4; jj++) {
    int j0 = j0g * 4 + jj;
    int w0 = j0 * 32 + j1c * 8;
    float f0, f1, f2, f3, f4, f5, f6, f7;
    if (w0 + 8 <= 252) {
      float4 a = *(const float4*)&s[w0];
      float4 bq = *(const float4*)&s[w0 + 4];
      f0 = a.x; f1 = a.y; f2 = a.z; f3 = a.w;
      f4 = bq.x; f5 = bq.y; f6 = bq.z; f7 = bq.w;
    } else {  // w0==248: cols 248..255 -> 248,249,250,251,250,249,248,247
      float4 a = *(const float4*)&s[244];
      float4 bq = *(const float4*)&s[248];
      f0 = bq.x; f1 = bq.y; f2 = bq.z; f3 = bq.w;
      f4 = bq.z; f5 = bq.y; f6 = bq.x; f7 = a.w;
    }
    psum[jj] = f0*f0 + f1*f1 + f2*f2 + f3*f3 + f4*f4 + f5*f5 + f6*f6 + f7*f7;
    uint4 o;
    o.x = f2bf(f0) | (f2bf(f1) << 16);
    o.y = f2bf(f2) | (f2bf(f3) << 16);
    o.z = f2bf(f4) | (f2bf(f5) << 16);
    o.w = f2bf(f6) | (f2bf(f7) << 16);
    *(uint4*)&dst[(size_t)(j0 * 32 + c) * 1024 + j1c * 8] = o;
  }

  #pragma unroll
  for (int jj = 0; jj < 4; jj++) {
    float ssum = psum[jj];
    ssum += __shfl_down(ssum, 2, 4);
    ssum += __shfl_down(ssum, 1, 4);
    if (j1c == 0) {
      int j0 = j0g * 4 + jj;
      atomicAdd(&svsum[(size_t)b * 2048 + i0 * 256 + j0 * 32 + c], ssum);
    }
  }
}

// ---------------------------------------------------------------------------
// GEMM NT: C[M][N] = A[M][K] * B[N][K]^T, bf16 in, fp32 acc.
// 1D grid, decode: b = flat&7 (XCD affinity), m, n of the remainder.
// MODE 0: store bf16 S * scale.  MODE 1: acc *= rsqrt(svsum[row]), scatter
// fp32 + crop.
// ---------------------------------------------------------------------------
template <int MODE>
__global__ __launch_bounds__(256, 4)
void gemm_nt(const unsigned short* __restrict__ A,
             const unsigned short* __restrict__ B,
             int K, int Asb, int Bsb, void* __restrict__ Cout, float scale,
             const float* __restrict__ sv) {
  __shared__ unsigned short lA[128 * 64];
  __shared__ unsigned short lB[128 * 64];
  __shared__ float svb[(MODE == 1) ? 128 : 1];

  const int flat = blockIdx.x;
  const int zz   = flat & 7;
  const int rr   = flat >> 3;
  const int my   = rr >> 3;
  const int nx   = rr & 7;

  const int tid  = threadIdx.x;
  const int lane = tid & 63;
  const int wave = tid >> 6;
  const int ln15 = lane & 15;
  const int q4   = lane >> 4;
  const int wm   = wave >> 1;
  const int wn   = wave & 1;
  const int m0   = my * 128;
  const int n0   = nx * 128;
  const unsigned short* Ab = A + (size_t)zz * Asb;
  const unsigned short* Bb = B + (size_t)zz * Bsb;

  if (MODE == 1 && tid < 128)
    svb[tid] = 1.f / fmaxf(sqrtf(sv[(size_t)zz * 2048 + m0 + tid]), 1e-12f);

  const int srow = lane >> 3;
  const int kcp  = lane & 7;
  const int kcl  = kcp ^ srow;      // xor-swizzled source chunk

  f32x4 acc[4][4] = {};

  for (int k0 = 0; k0 < K; k0 += 64) {
    #pragma unroll
    for (int r = 0; r < 4; r++) {
      int rowg = wave * 32 + r * 8;
      int row  = rowg + srow;
      load_lds16(&Ab[(size_t)(m0 + row) * K + k0 + kcl * 8], &lA[rowg * 64]);
      load_lds16(&Bb[(size_t)(n0 + row) * K + k0 + kcl * 8], &lB[rowg * 64]);
    }
    __syncthreads();
    #pragma unroll
    for (int kk = 0; kk < 2; kk++) {
      bf16x8 af[4], bfr[4];
      #pragma unroll
      for (int mt = 0; mt < 4; mt++) {
        int row = wm * 64 + mt * 16 + ln15;
        int pc  = (kk * 4 + q4) ^ (row & 7);
        af[mt] = *(const bf16x8*)&lA[row * 64 + pc * 8];
      }
      #pragma unroll
      for (int nt = 0; nt < 4; nt++) {
        int row = wn * 64 + nt * 16 + ln15;
        int pc  = (kk * 4 + q4) ^ (row & 7);
        bfr[nt] = *(const bf16x8*)&lB[row * 64 + pc * 8];
      }
      #pragma unroll
      for (int mt = 0; mt < 4; mt++)
        #pragma unroll
        for (int nt = 0; nt < 4; nt++)
          acc[mt][nt] = __builtin_amdgcn_mfma_f32_16x16x32_bf16(
              af[mt], bfr[nt], acc[mt][nt], 0, 0, 0);
    }
    __syncthreads();
  }

  if (MODE == 0) {
    unsigned short* Sb = (unsigned short*)Cout + (size_t)zz * 1024 * 1024;
    #pragma unroll
    for (int mt = 0; mt < 4; mt++) {
      #pragma unroll
      for (int nt = 0; nt < 4; nt++) {
        int col = n0 + wn * 64 + nt * 16 + ln15;
        #pragma unroll
        for (int rg = 0; rg < 4; rg++) {
          int rowi = m0 + wm * 64 + mt * 16 + q4 * 4 + rg;
          Sb[(size_t)rowi * 1024 + col] = (unsigned short)f2bf(acc[mt][nt][rg] * scale);
        }
      }
    }
  } else {
    float* Ob = (float*)Cout;
    #pragma unroll
    for (int mt = 0; mt < 4; mt++) {
      #pragma unroll
      for (int nt = 0; nt < 4; nt++) {
        int l  = n0 + wn * 64 + nt * 16 + ln15;
        int i1 = l >> 5, j1 = l & 31;
        #pragma unroll
        for (int rg = 0; rg < 4; rg++) {
          int rloc = wm * 64 + mt * 16 + q4 * 4 + rg;
          int dp = m0 + rloc;
          int c  = dp & 31;
          int j0 = (dp >> 5) & 7;
          int i0 = dp >> 8;
          int h = i0 * 32 + i1;
          int w = j0 * 32 + j1;
          if (h < 252 && w < 252)
            Ob[(((size_t)zz * 32 + c) * 252 + h) * 252 + w] =
                acc[mt][nt][rg] * svb[rloc];
        }
      }
    }
  }
}

// ---------------------------------------------------------------------------
// Kernel 5: row softmax over S (bf16, in place -> P). Block per row (b,l).
// ---------------------------------------------------------------------------
__global__ void softmax_kernel(unsigned short* __restrict__ S) {
  unsigned short* row = S + (size_t)blockIdx.x * 1024;
  int tid  = threadIdx.x;
  int lane = tid & 63;
  int wid  = tid >> 6;

  uint2 u = *(const uint2*)&row[tid * 4];
  float x0 = bf2f(u.x & 0xFFFF);
  float x1 = bf2f(u.x >> 16);
  float x2 = bf2f(u.y & 0xFFFF);
  float x3 = bf2f(u.y >> 16);

  __shared__ float red[8];
  float mx = fmaxf(fmaxf(x0, x1), fmaxf(x2, x3));
  #pragma unroll
  for (int off = 32; off > 0; off >>= 1) mx = fmaxf(mx, __shfl_down(mx, off));
  if (lane == 0) red[wid] = mx;
  __syncthreads();
  if (tid == 0)
    red[4] = fmaxf(fmaxf(red[0], red[1]), fmaxf(red[2], red[3]));
  __syncthreads();
  float bm = red[4];

  float e0 = __expf(x0 - bm), e1 = __expf(x1 - bm);
  float e2 = __expf(x2 - bm), e3 = __expf(x3 - bm);
  float s = e0 + e1 + e2 + e3;
  #pragma unroll
  for (int off = 32; off > 0; off >>= 1) s += __shfl_down(s, off);
  if (lane == 0) red[wid] = s;
  __syncthreads();
  if (tid == 0) red[5] = 1.0f / (red[0] + red[1] + red[2] + red[3]);
  __syncthreads();
  float inv = red[5];

  unsigned int o0 = f2bf(e0 * inv) | (f2bf(e1 * inv) << 16);
  unsigned int o1 = f2bf(e2 * inv) | (f2bf(e3 * inv) << 16);
  uint2 o; o.x = o0; o.y = o1;
  *(uint2*)&row[tid * 4] = o;
}

// ---------------------------------------------------------------------------
extern "C" void kernel_launch(void* const* d_in, const int* in_sizes, int n_in,
                              void* d_out, int out_size, void* d_ws, size_t ws_size,
                              hipStream_t stream) {
  const float* q = (const float*)d_in[0];
  const float* k = (const float*)d_in[1];
  const float* v = (const float*)d_in[2];
  float* out = (float*)d_out;

  char* ws = (char*)d_ws;
  float* sv = (float*)ws;                                       // 8*2048*4 = 64 KB
  unsigned short* Qh = (unsigned short*)(ws + 196608);          // 32 MB
  unsigned short* Kh = Qh + (size_t)8 * 1024 * 2048;            // 32 MB
  unsigned short* Vt = Kh + (size_t)8 * 1024 * 2048;            // 32 MB
  unsigned short* S  = Vt + (size_t)8 * 2048 * 1024;            // 16 MB

  const float SIM_SCALE = 0.02209708691207961f;  // 2048^-0.5

  hipMemsetAsync(sv, 0, (size_t)8 * 2048 * sizeof(float), stream);
  pack_qk_fused<<<512, 256, 0, stream>>>(q, k, Qh, Kh);
  pack_v_kernel<<<2048, 256, 0, stream>>>(v, Vt, sv);
  gemm_nt<0><<<512, 256, 0, stream>>>(
      Qh, Kh, 2048, 1024 * 2048, 1024 * 2048, (void*)S, SIM_SCALE, nullptr);
  softmax_kernel<<<8192, 256, 0, stream>>>(S);
  gemm_nt<1><<<1024, 256, 0, stream>>>(
      Vt, S, 1024, 2048 * 1024, 1024 * 1024, (void*)out, 1.0f, sv);
}

// Round 11
// 369.358 us; speedup vs baseline: 1.0966x; 1.0966x over previous
//
#include <hip/hip_runtime.h>
#include <cstdint>
#include <cstddef>

// ---------------------------------------------------------------------------
// cross_attention: b=8, c=32, 252x252, ws=8 -> padded 256x256.
// tokens l=(i1,j1) in 32x32, features d'=(i0*256 + j0*32 + c) in 2048.
// Pipeline (R13): pack_qk_fused v5 — per-WINDOW LDS-resident tile.
//   R10 evidence: v4 (136 KB tile, 1 blk/CU) achieved write-once
//   (WRITE 131->64 MB, bytes 262->161 MB) but occupancy 10.5% collapsed BW
//   2.8->1.36 TB/s -> net regression. v5 keeps write-once but halves the
//   tile: block = (t,b,i0,j0) owns one 32x32-pixel window x 32ch ->
//   tile 1024 x 36-stride bf16 = 72 KB -> 2 blocks/CU, 8 waves (v3's
//   occupancy with v4's byte count). Norms stay block-local.
//   -> pack_v (raw bf16 Vt + fused svsum atomics) -> S = Qh Kh^T * 2048^-0.5
//   -> softmax -> Ot = (rsqrt(svsum).*Vt) P^T fused scatter.
// ---------------------------------------------------------------------------

typedef __bf16 bf16x8 __attribute__((ext_vector_type(8)));
typedef float  f32x4  __attribute__((ext_vector_type(4)));

__device__ __forceinline__ unsigned int f2bf(float f) {
  unsigned int u = __builtin_bit_cast(unsigned int, f);
  u += 0x7FFFu + ((u >> 16) & 1u);   // round-to-nearest-even
  return u >> 16;
}
__device__ __forceinline__ float bf2f(unsigned int h) {
  return __builtin_bit_cast(float, h << 16);
}

__device__ __forceinline__ void load_lds16(const void* g, void* l) {
  __builtin_amdgcn_global_load_lds(
      (const __attribute__((address_space(1))) void*)g,
      (__attribute__((address_space(3))) void*)l, 16, 0, 0);
}

// ---------------------------------------------------------------------------
// Kernel 1 (v5): fused norm+pack for Q,K, per-window LDS tile.
// Block = (t, b, i0, j0): 32ch x 32h x 32w window = 1024 tokens x 32 d'.
// Phase A: thread (c = tid>>3, ch = tid&7) reads one float4/row for 32 rows
//   (8 lanes x 16B = 128B contiguous per (c,row)), accumulates weighted
//   squares (reflect weights: 247..250 x2, >=252 -> 0; row x col product
//   handles corners), writes raw bf16 into tile[l*36 + c] (stride 36 shorts
//   = 72B: 8B-aligned uint2 reads, spread banks).
// Phase B: 8-way reduce -> sclt[c] = 1/max(||.||,1e-12).
// Phase C': thread (qd = tid&7 c-quad, lr = tid>>3) scales uint2 and stores
//   to X[l*2048 + i0*256 + j0*32 + qd*4]; 8 qd lanes = 64B/token segment.
//   Qh/Kh written ONCE (write-once validated in R10: WRITE 131->64 MB).
// Tail: j0==7, ch==7 (w 252..255) mirrors values from 250..247, weight 0;
//   rows h>=252 mirrored via hs with row weight 0.
// ---------------------------------------------------------------------------
__global__ __launch_bounds__(256)
void pack_qk_fused(const float* __restrict__ q, const float* __restrict__ k,
                   unsigned short* __restrict__ Qh,
                   unsigned short* __restrict__ Kh) {
  int bx  = blockIdx.x;          // grid 1024
  int t   = bx >> 9;             // 0..1
  int b   = (bx >> 6) & 7;
  int i0  = (bx >> 3) & 7;
  int j0  = bx & 7;
  const float* xb = (t ? k : q) + (size_t)b * 32 * 63504;

  __shared__ unsigned short tile[1024 * 36];   // 72 KB -> 2 blocks/CU
  __shared__ float red[256];
  __shared__ float sclt[32];

  int tid = threadIdx.x;
  int ch  = tid & 7;               // w-chunk (4 floats)
  int c   = tid >> 3;              // channel 0..31

  int wbase = j0 * 32 + ch * 4;
  float we[4];
  #pragma unroll
  for (int e = 0; e < 4; e++) {
    int w = wbase + e;
    we[e] = (w >= 252) ? 0.f : (((unsigned)(w - 247) <= 3u) ? 2.f : 1.f);
  }
  bool tail = (wbase == 252);      // only j0==7, ch==7

  float pa = 0.f;
  unsigned short* X = (t ? Kh : Qh) + (size_t)b * 1024 * 2048;
  const float* csrc = xb + (size_t)c * 63504;

  // ---- Phase A: stage + squares (no barriers; 32 independent loads) ----
  for (int i1 = 0; i1 < 32; i1++) {
    int h  = i0 * 32 + i1;
    int hs = (h < 252) ? h : 502 - h;
    float rw = (h >= 252) ? 0.f : (((unsigned)(h - 247) <= 3u) ? 2.f : 1.f);
    const float* rowp = csrc + (size_t)hs * 252;

    float4 vv;
    if (!tail) {
      vv = *(const float4*)&rowp[wbase];
    } else {  // w 252..255 mirror to 250,249,248,247
      vv.x = rowp[250]; vv.y = rowp[249]; vv.z = rowp[248]; vv.w = rowp[247];
    }
    pa += rw * (we[0] * vv.x * vv.x + we[1] * vv.y * vv.y +
                we[2] * vv.z * vv.z + we[3] * vv.w * vv.w);
    int lbase = i1 * 32 + ch * 4;          // token = i1*32 + j1
    unsigned short* tp = &tile[(size_t)lbase * 36 + c];
    tp[0]   = (unsigned short)f2bf(vv.x);
    tp[36]  = (unsigned short)f2bf(vv.y);
    tp[72]  = (unsigned short)f2bf(vv.z);
    tp[108] = (unsigned short)f2bf(vv.w);
  }
  __syncthreads();

  // ---- Phase B: reduce 8 chunk-partials per channel -> 32 scales ----
  red[tid] = pa;
  __syncthreads();
  if (tid < 32) {
    float s = 0.f;
    #pragma unroll
    for (int u = 0; u < 8; u++) s += red[tid * 8 + u];
    sclt[tid] = 1.f / fmaxf(sqrtf(s), 1e-12f);
  }
  __syncthreads();

  // ---- Phase C': scaled write-out, each output byte written once ----
  {
    int qd = tid & 7;              // c quad: c = qd*4 .. qd*4+3
    int lr = tid >> 3;             // token row 0..31
    float sc[4];
    #pragma unroll
    for (int m = 0; m < 4; m++) sc[m] = sclt[qd * 4 + m];
    unsigned short* Xb = &X[i0 * 256 + j0 * 32 + qd * 4];
    #pragma unroll 4
    for (int it = 0; it < 32; it++) {
      int l = it * 32 + lr;
      uint2 u = *(const uint2*)&tile[(size_t)l * 36 + qd * 4];
      uint2 o2;
      o2.x = f2bf(bf2f(u.x & 0xFFFF) * sc[0]) |
             (f2bf(bf2f(u.x >> 16)   * sc[1]) << 16);
      o2.y = f2bf(bf2f(u.y & 0xFFFF) * sc[2]) |
             (f2bf(bf2f(u.y >> 16)   * sc[3]) << 16);
      *(uint2*)&Xb[(size_t)l * 2048] = o2;
    }
  }
}

// ---------------------------------------------------------------------------
// Kernel 2: pack V to bf16 Vt[d'][l] — RAW (scale folded into gemm2), no LDS.
// Fused: sum-of-squares per (b, d') row accumulated into svsum via 4-lane
// shfl reduce + one atomicAdd per (c, j0) per block. svsum zeroed via
// hipMemsetAsync before launch.
// ---------------------------------------------------------------------------
__global__ void pack_v_kernel(const float* __restrict__ v,
                              unsigned short* __restrict__ Vt,
                              float* __restrict__ svsum) {
  int bx = blockIdx.x;
  int b  = bx >> 8;
  int i0 = (bx >> 5) & 7;
  int i1 = bx & 31;
  int h  = i0 * 32 + i1;
  int hs = (h < 252) ? h : 502 - h;
  const float* src = v + (size_t)b * 32 * 63504 + (size_t)hs * 252;
  unsigned short* dst = Vt + (size_t)b * 2048 * 1024
                           + (size_t)(i0 * 256) * 1024 + i1 * 32;

  int tid = threadIdx.x;
  int j1c = tid & 3;
  int c   = (tid >> 2) & 31;
  int j0g = tid >> 7;          // 0..1
  const float* s = src + (size_t)c * 63504;

  float psum[4];

  #pragma unroll
  for (int jj = 0; jj < 4; jj++) {
    int j0 = j0g * 4 + jj;
    int w0 = j0 * 32 + j1c * 8;
    float f0, f1, f2, f3, f4, f5, f6, f7;
    if (w0 + 8 <= 252) {
      float4 a = *(const float4*)&s[w0];
      float4 bq = *(const float4*)&s[w0 + 4];
      f0 = a.x; f1 = a.y; f2 = a.z; f3 = a.w;
      f4 = bq.x; f5 = bq.y; f6 = bq.z; f7 = bq.w;
    } else {  // w0==248: cols 248..255 -> 248,249,250,251,250,249,248,247
      float4 a = *(const float4*)&s[244];
      float4 bq = *(const float4*)&s[248];
      f0 = bq.x; f1 = bq.y; f2 = bq.z; f3 = bq.w;
      f4 = bq.z; f5 = bq.y; f6 = bq.x; f7 = a.w;
    }
    psum[jj] = f0*f0 + f1*f1 + f2*f2 + f3*f3 + f4*f4 + f5*f5 + f6*f6 + f7*f7;
    uint4 o;
    o.x = f2bf(f0) | (f2bf(f1) << 16);
    o.y = f2bf(f2) | (f2bf(f3) << 16);
    o.z = f2bf(f4) | (f2bf(f5) << 16);
    o.w = f2bf(f6) | (f2bf(f7) << 16);
    *(uint4*)&dst[(size_t)(j0 * 32 + c) * 1024 + j1c * 8] = o;
  }

  #pragma unroll
  for (int jj = 0; jj < 4; jj++) {
    float ssum = psum[jj];
    ssum += __shfl_down(ssum, 2, 4);
    ssum += __shfl_down(ssum, 1, 4);
    if (j1c == 0) {
      int j0 = j0g * 4 + jj;
      atomicAdd(&svsum[(size_t)b * 2048 + i0 * 256 + j0 * 32 + c], ssum);
    }
  }
}

// ---------------------------------------------------------------------------
// GEMM NT: C[M][N] = A[M][K] * B[N][K]^T, bf16 in, fp32 acc.
// 1D grid, decode: b = flat&7 (XCD affinity), m, n of the remainder.
// MODE 0: store bf16 S * scale.  MODE 1: acc *= rsqrt(svsum[row]), scatter
// fp32 + crop.
// ---------------------------------------------------------------------------
template <int MODE>
__global__ __launch_bounds__(256, 4)
void gemm_nt(const unsigned short* __restrict__ A,
             const unsigned short* __restrict__ B,
             int K, int Asb, int Bsb, void* __restrict__ Cout, float scale,
             const float* __restrict__ sv) {
  __shared__ unsigned short lA[128 * 64];
  __shared__ unsigned short lB[128 * 64];
  __shared__ float svb[(MODE == 1) ? 128 : 1];

  const int flat = blockIdx.x;
  const int zz   = flat & 7;
  const int rr   = flat >> 3;
  const int my   = rr >> 3;
  const int nx   = rr & 7;

  const int tid  = threadIdx.x;
  const int lane = tid & 63;
  const int wave = tid >> 6;
  const int ln15 = lane & 15;
  const int q4   = lane >> 4;
  const int wm   = wave >> 1;
  const int wn   = wave & 1;
  const int m0   = my * 128;
  const int n0   = nx * 128;
  const unsigned short* Ab = A + (size_t)zz * Asb;
  const unsigned short* Bb = B + (size_t)zz * Bsb;

  if (MODE == 1 && tid < 128)
    svb[tid] = 1.f / fmaxf(sqrtf(sv[(size_t)zz * 2048 + m0 + tid]), 1e-12f);

  const int srow = lane >> 3;
  const int kcp  = lane & 7;
  const int kcl  = kcp ^ srow;      // xor-swizzled source chunk

  f32x4 acc[4][4] = {};

  for (int k0 = 0; k0 < K; k0 += 64) {
    #pragma unroll
    for (int r = 0; r < 4; r++) {
      int rowg = wave * 32 + r * 8;
      int row  = rowg + srow;
      load_lds16(&Ab[(size_t)(m0 + row) * K + k0 + kcl * 8], &lA[rowg * 64]);
      load_lds16(&Bb[(size_t)(n0 + row) * K + k0 + kcl * 8], &lB[rowg * 64]);
    }
    __syncthreads();
    #pragma unroll
    for (int kk = 0; kk < 2; kk++) {
      bf16x8 af[4], bfr[4];
      #pragma unroll
      for (int mt = 0; mt < 4; mt++) {
        int row = wm * 64 + mt * 16 + ln15;
        int pc  = (kk * 4 + q4) ^ (row & 7);
        af[mt] = *(const bf16x8*)&lA[row * 64 + pc * 8];
      }
      #pragma unroll
      for (int nt = 0; nt < 4; nt++) {
        int row = wn * 64 + nt * 16 + ln15;
        int pc  = (kk * 4 + q4) ^ (row & 7);
        bfr[nt] = *(const bf16x8*)&lB[row * 64 + pc * 8];
      }
      #pragma unroll
      for (int mt = 0; mt < 4; mt++)
        #pragma unroll
        for (int nt = 0; nt < 4; nt++)
          acc[mt][nt] = __builtin_amdgcn_mfma_f32_16x16x32_bf16(
              af[mt], bfr[nt], acc[mt][nt], 0, 0, 0);
    }
    __syncthreads();
  }

  if (MODE == 0) {
    unsigned short* Sb = (unsigned short*)Cout + (size_t)zz * 1024 * 1024;
    #pragma unroll
    for (int mt = 0; mt < 4; mt++) {
      #pragma unroll
      for (int nt = 0; nt < 4; nt++) {
        int col = n0 + wn * 64 + nt * 16 + ln15;
        #pragma unroll
        for (int rg = 0; rg < 4; rg++) {
          int rowi = m0 + wm * 64 + mt * 16 + q4 * 4 + rg;
          Sb[(size_t)rowi * 1024 + col] = (unsigned short)f2bf(acc[mt][nt][rg] * scale);
        }
      }
    }
  } else {
    float* Ob = (float*)Cout;
    #pragma unroll
    for (int mt = 0; mt < 4; mt++) {
      #pragma unroll
      for (int nt = 0; nt < 4; nt++) {
        int l  = n0 + wn * 64 + nt * 16 + ln15;
        int i1 = l >> 5, j1 = l & 31;
        #pragma unroll
        for (int rg = 0; rg < 4; rg++) {
          int rloc = wm * 64 + mt * 16 + q4 * 4 + rg;
          int dp = m0 + rloc;
          int c  = dp & 31;
          int j0 = (dp >> 5) & 7;
          int i0 = dp >> 8;
          int h = i0 * 32 + i1;
          int w = j0 * 32 + j1;
          if (h < 252 && w < 252)
            Ob[(((size_t)zz * 32 + c) * 252 + h) * 252 + w] =
                acc[mt][nt][rg] * svb[rloc];
        }
      }
    }
  }
}

// ---------------------------------------------------------------------------
// Kernel 5: row softmax over S (bf16, in place -> P). Block per row (b,l).
// ---------------------------------------------------------------------------
__global__ void softmax_kernel(unsigned short* __restrict__ S) {
  unsigned short* row = S + (size_t)blockIdx.x * 1024;
  int tid  = threadIdx.x;
  int lane = tid & 63;
  int wid  = tid >> 6;

  uint2 u = *(const uint2*)&row[tid * 4];
  float x0 = bf2f(u.x & 0xFFFF);
  float x1 = bf2f(u.x >> 16);
  float x2 = bf2f(u.y & 0xFFFF);
  float x3 = bf2f(u.y >> 16);

  __shared__ float red[8];
  float mx = fmaxf(fmaxf(x0, x1), fmaxf(x2, x3));
  #pragma unroll
  for (int off = 32; off > 0; off >>= 1) mx = fmaxf(mx, __shfl_down(mx, off));
  if (lane == 0) red[wid] = mx;
  __syncthreads();
  if (tid == 0)
    red[4] = fmaxf(fmaxf(red[0], red[1]), fmaxf(red[2], red[3]));
  __syncthreads();
  float bm = red[4];

  float e0 = __expf(x0 - bm), e1 = __expf(x1 - bm);
  float e2 = __expf(x2 - bm), e3 = __expf(x3 - bm);
  float s = e0 + e1 + e2 + e3;
  #pragma unroll
  for (int off = 32; off > 0; off >>= 1) s += __shfl_down(s, off);
  if (lane == 0) red[wid] = s;
  __syncthreads();
  if (tid == 0) red[5] = 1.0f / (red[0] + red[1] + red[2] + red[3]);
  __syncthreads();
  float inv = red[5];

  unsigned int o0 = f2bf(e0 * inv) | (f2bf(e1 * inv) << 16);
  unsigned int o1 = f2bf(e2 * inv) | (f2bf(e3 * inv) << 16);
  uint2 o; o.x = o0; o.y = o1;
  *(uint2*)&row[tid * 4] = o;
}

// ---------------------------------------------------------------------------
extern "C" void kernel_launch(void* const* d_in, const int* in_sizes, int n_in,
                              void* d_out, int out_size, void* d_ws, size_t ws_size,
                              hipStream_t stream) {
  const float* q = (const float*)d_in[0];
  const float* k = (const float*)d_in[1];
  const float* v = (const float*)d_in[2];
  float* out = (float*)d_out;

  char* ws = (char*)d_ws;
  float* sv = (float*)ws;                                       // 8*2048*4 = 64 KB
  unsigned short* Qh = (unsigned short*)(ws + 196608);          // 32 MB
  unsigned short* Kh = Qh + (size_t)8 * 1024 * 2048;            // 32 MB
  unsigned short* Vt = Kh + (size_t)8 * 1024 * 2048;            // 32 MB
  unsigned short* S  = Vt + (size_t)8 * 2048 * 1024;            // 16 MB

  const float SIM_SCALE = 0.02209708691207961f;  // 2048^-0.5

  hipMemsetAsync(sv, 0, (size_t)8 * 2048 * sizeof(float), stream);
  pack_qk_fused<<<1024, 256, 0, stream>>>(q, k, Qh, Kh);
  pack_v_kernel<<<2048, 256, 0, stream>>>(v, Vt, sv);
  gemm_nt<0><<<512, 256, 0, stream>>>(
      Qh, Kh, 2048, 1024 * 2048, 1024 * 2048, (void*)S, SIM_SCALE, nullptr);
  softmax_kernel<<<8192, 256, 0, stream>>>(S);
  gemm_nt<1><<<1024, 256, 0, stream>>>(
      Vt, S, 1024, 2048 * 1024, 1024 * 1024, (void*)out, 1.0f, sv);
}

// Round 14
// 356.300 us; speedup vs baseline: 1.1368x; 1.0366x over previous
//
#include <hip/hip_runtime.h>
#include <cstdint>
#include <cstddef>

// ---------------------------------------------------------------------------
// cross_attention: b=8, c=32, 252x252, ws=8 -> padded 256x256.
// tokens l=(i1,j1) in 32x32, features d'=(i0*256 + j0*32 + c) in 2048.
// Pipeline (R14, resubmitted x2): pack_qk_fused v6 — v5's per-window
//   write-once tile with 512-THREAD blocks: 72 KB tile still fits
//   2 blocks/CU -> 16 waves/CU resident (2x v5's TLP), half work/thread.
//   R11 evidence: v5 hit the byte target (120R + 65.5W MB) but only
//   2.3 TB/s at 8 waves/CU; v3 showed 2.8 TB/s is reachable on this shape.
//   -> pack_v (raw bf16 Vt + fused svsum atomics) -> S = Qh Kh^T * 2048^-0.5
//   -> softmax -> Ot = (rsqrt(svsum).*Vt) P^T fused scatter.
// R12/R13 audits: decode tid = c*16 + i1h*8 + ch; every (l,c) cell staged
// once; red layout matches reduce; C' covers 1024x32 exactly; LDS 75,904 B
// x2 < 160 KB (LDS-limited at 2 blk/CU, VGPR non-binding); launch_bounds
// (512) = launch dim.
// ---------------------------------------------------------------------------

typedef __bf16 bf16x8 __attribute__((ext_vector_type(8)));
typedef float  f32x4  __attribute__((ext_vector_type(4)));

__device__ __forceinline__ unsigned int f2bf(float f) {
  unsigned int u = __builtin_bit_cast(unsigned int, f);
  u += 0x7FFFu + ((u >> 16) & 1u);   // round-to-nearest-even
  return u >> 16;
}
__device__ __forceinline__ float bf2f(unsigned int h) {
  return __builtin_bit_cast(float, h << 16);
}

__device__ __forceinline__ void load_lds16(const void* g, void* l) {
  __builtin_amdgcn_global_load_lds(
      (const __attribute__((address_space(1))) void*)g,
      (__attribute__((address_space(3))) void*)l, 16, 0, 0);
}

// ---------------------------------------------------------------------------
// Kernel 1 (v6): fused norm+pack for Q,K, per-window LDS tile, 512 threads.
// Block = (t, b, i0, j0): 32ch x 32h x 32w window = 1024 tokens x 32 d'.
// Phase A: thread (c = tid>>4, i1h = (tid>>3)&1, ch = tid&7) reads one
//   float4/row for 16 rows (i1 = i1h*16 + r), accumulates weighted squares
//   (reflect weights: 247..250 x2, >=252 -> 0; row x col product handles
//   corners), writes raw bf16 into tile[l*36 + c] (stride-36 shorts).
// Phase B: red[512] -> 16-way reduce per channel -> sclt[c] = rsqrt.
// Phase C': thread (qd = tid&7, lidx = tid>>3) scales uint2 and stores 16
//   tokens (l = it*64 + lidx) to X[l*2048 + i0*256 + j0*32 + qd*4].
//   Qh/Kh written ONCE (write-once validated R10/R11).
// Tail: j0==7, ch==7 (w 252..255) mirrors values from 250..247, weight 0;
//   rows h>=252 mirrored via hs with row weight 0.
// ---------------------------------------------------------------------------
__global__ __launch_bounds__(512)
void pack_qk_fused(const float* __restrict__ q, const float* __restrict__ k,
                   unsigned short* __restrict__ Qh,
                   unsigned short* __restrict__ Kh) {
  int bx  = blockIdx.x;          // grid 1024
  int t   = bx >> 9;             // 0..1
  int b   = (bx >> 6) & 7;
  int i0  = (bx >> 3) & 7;
  int j0  = bx & 7;
  const float* xb = (t ? k : q) + (size_t)b * 32 * 63504;

  __shared__ unsigned short tile[1024 * 36];   // 72 KB -> 2 blocks/CU
  __shared__ float red[512];
  __shared__ float sclt[32];

  int tid = threadIdx.x;
  int ch  = tid & 7;               // w-chunk (4 floats)
  int i1h = (tid >> 3) & 1;        // row half
  int c   = tid >> 4;              // channel 0..31

  int wbase = j0 * 32 + ch * 4;
  float we[4];
  #pragma unroll
  for (int e = 0; e < 4; e++) {
    int w = wbase + e;
    we[e] = (w >= 252) ? 0.f : (((unsigned)(w - 247) <= 3u) ? 2.f : 1.f);
  }
  bool tail = (wbase == 252);      // only j0==7, ch==7

  float pa = 0.f;
  unsigned short* X = (t ? Kh : Qh) + (size_t)b * 1024 * 2048;
  const float* csrc = xb + (size_t)c * 63504;

  // ---- Phase A: stage + squares (no barriers; 16 independent loads) ----
  #pragma unroll 4
  for (int r = 0; r < 16; r++) {
    int i1 = i1h * 16 + r;
    int h  = i0 * 32 + i1;
    int hs = (h < 252) ? h : 502 - h;
    float rw = (h >= 252) ? 0.f : (((unsigned)(h - 247) <= 3u) ? 2.f : 1.f);
    const float* rowp = csrc + (size_t)hs * 252;

    float4 vv;
    if (!tail) {
      vv = *(const float4*)&rowp[wbase];
    } else {  // w 252..255 mirror to 250,249,248,247
      vv.x = rowp[250]; vv.y = rowp[249]; vv.z = rowp[248]; vv.w = rowp[247];
    }
    pa += rw * (we[0] * vv.x * vv.x + we[1] * vv.y * vv.y +
                we[2] * vv.z * vv.z + we[3] * vv.w * vv.w);
    int lbase = i1 * 32 + ch * 4;          // token = i1*32 + j1
    unsigned short* tp = &tile[(size_t)lbase * 36 + c];
    tp[0]   = (unsigned short)f2bf(vv.x);
    tp[36]  = (unsigned short)f2bf(vv.y);
    tp[72]  = (unsigned short)f2bf(vv.z);
    tp[108] = (unsigned short)f2bf(vv.w);
  }
  __syncthreads();

  // ---- Phase B: reduce 16 partials per channel -> 32 scales ----
  red[tid] = pa;
  __syncthreads();
  if (tid < 32) {
    float s = 0.f;
    #pragma unroll
    for (int u = 0; u < 16; u++) s += red[tid * 16 + u];
    sclt[tid] = 1.f / fmaxf(sqrtf(s), 1e-12f);
  }
  __syncthreads();

  // ---- Phase C': scaled write-out, each output byte written once ----
  {
    int qd   = tid & 7;            // c quad: c = qd*4 .. qd*4+3
    int lidx = tid >> 3;           // 0..63
    float sc[4];
    #pragma unroll
    for (int m = 0; m < 4; m++) sc[m] = sclt[qd * 4 + m];
    unsigned short* Xb = &X[i0 * 256 + j0 * 32 + qd * 4];
    #pragma unroll 4
    for (int it = 0; it < 16; it++) {
      int l = it * 64 + lidx;
      uint2 u = *(const uint2*)&tile[(size_t)l * 36 + qd * 4];
      uint2 o2;
      o2.x = f2bf(bf2f(u.x & 0xFFFF) * sc[0]) |
             (f2bf(bf2f(u.x >> 16)   * sc[1]) << 16);
      o2.y = f2bf(bf2f(u.y & 0xFFFF) * sc[2]) |
             (f2bf(bf2f(u.y >> 16)   * sc[3]) << 16);
      *(uint2*)&Xb[(size_t)l * 2048] = o2;
    }
  }
}

// ---------------------------------------------------------------------------
// Kernel 2: pack V to bf16 Vt[d'][l] — RAW (scale folded into gemm2), no LDS.
// Fused: sum-of-squares per (b, d') row accumulated into svsum via 4-lane
// shfl reduce + one atomicAdd per (c, j0) per block. svsum zeroed via
// hipMemsetAsync before launch.
// ---------------------------------------------------------------------------
__global__ void pack_v_kernel(const float* __restrict__ v,
                              unsigned short* __restrict__ Vt,
                              float* __restrict__ svsum) {
  int bx = blockIdx.x;
  int b  = bx >> 8;
  int i0 = (bx >> 5) & 7;
  int i1 = bx & 31;
  int h  = i0 * 32 + i1;
  int hs = (h < 252) ? h : 502 - h;
  const float* src = v + (size_t)b * 32 * 63504 + (size_t)hs * 252;
  unsigned short* dst = Vt + (size_t)b * 2048 * 1024
                           + (size_t)(i0 * 256) * 1024 + i1 * 32;

  int tid = threadIdx.x;
  int j1c = tid & 3;
  int c   = (tid >> 2) & 31;
  int j0g = tid >> 7;          // 0..1
  const float* s = src + (size_t)c * 63504;

  float psum[4];

  #pragma unroll
  for (int jj = 0; jj < 4; jj++) {
    int j0 = j0g * 4 + jj;
    int w0 = j0 * 32 + j1c * 8;
    float f0, f1, f2, f3, f4, f5, f6, f7;
    if (w0 + 8 <= 252) {
      float4 a = *(const float4*)&s[w0];
      float4 bq = *(const float4*)&s[w0 + 4];
      f0 = a.x; f1 = a.y; f2 = a.z; f3 = a.w;
      f4 = bq.x; f5 = bq.y; f6 = bq.z; f7 = bq.w;
    } else {  // w0==248: cols 248..255 -> 248,249,250,251,250,249,248,247
      float4 a = *(const float4*)&s[244];
      float4 bq = *(const float4*)&s[248];
      f0 = bq.x; f1 = bq.y; f2 = bq.z; f3 = bq.w;
      f4 = bq.z; f5 = bq.y; f6 = bq.x; f7 = a.w;
    }
    psum[jj] = f0*f0 + f1*f1 + f2*f2 + f3*f3 + f4*f4 + f5*f5 + f6*f6 + f7*f7;
    uint4 o;
    o.x = f2bf(f0) | (f2bf(f1) << 16);
    o.y = f2bf(f2) | (f2bf(f3) << 16);
    o.z = f2bf(f4) | (f2bf(f5) << 16);
    o.w = f2bf(f6) | (f2bf(f7) << 16);
    *(uint4*)&dst[(size_t)(j0 * 32 + c) * 1024 + j1c * 8] = o;
  }

  #pragma unroll
  for (int jj = 0; jj < 4; jj++) {
    float ssum = psum[jj];
    ssum += __shfl_down(ssum, 2, 4);
    ssum += __shfl_down(ssum, 1, 4);
    if (j1c == 0) {
      int j0 = j0g * 4 + jj;
      atomicAdd(&svsum[(size_t)b * 2048 + i0 * 256 + j0 * 32 + c], ssum);
    }
  }
}

// ---------------------------------------------------------------------------
// GEMM NT: C[M][N] = A[M][K] * B[N][K]^T, bf16 in, fp32 acc.
// 1D grid, decode: b = flat&7 (XCD affinity), m, n of the remainder.
// MODE 0: store bf16 S * scale.  MODE 1: acc *= rsqrt(svsum[row]), scatter
// fp32 + crop.
// ---------------------------------------------------------------------------
template <int MODE>
__global__ __launch_bounds__(256, 4)
void gemm_nt(const unsigned short* __restrict__ A,
             const unsigned short* __restrict__ B,
             int K, int Asb, int Bsb, void* __restrict__ Cout, float scale,
             const float* __restrict__ sv) {
  __shared__ unsigned short lA[128 * 64];
  __shared__ unsigned short lB[128 * 64];
  __shared__ float svb[(MODE == 1) ? 128 : 1];

  const int flat = blockIdx.x;
  const int zz   = flat & 7;
  const int rr   = flat >> 3;
  const int my   = rr >> 3;
  const int nx   = rr & 7;

  const int tid  = threadIdx.x;
  const int lane = tid & 63;
  const int wave = tid >> 6;
  const int ln15 = lane & 15;
  const int q4   = lane >> 4;
  const int wm   = wave >> 1;
  const int wn   = wave & 1;
  const int m0   = my * 128;
  const int n0   = nx * 128;
  const unsigned short* Ab = A + (size_t)zz * Asb;
  const unsigned short* Bb = B + (size_t)zz * Bsb;

  if (MODE == 1 && tid < 128)
    svb[tid] = 1.f / fmaxf(sqrtf(sv[(size_t)zz * 2048 + m0 + tid]), 1e-12f);

  const int srow = lane >> 3;
  const int kcp  = lane & 7;
  const int kcl  = kcp ^ srow;      // xor-swizzled source chunk

  f32x4 acc[4][4] = {};

  for (int k0 = 0; k0 < K; k0 += 64) {
    #pragma unroll
    for (int r = 0; r < 4; r++) {
      int rowg = wave * 32 + r * 8;
      int row  = rowg + srow;
      load_lds16(&Ab[(size_t)(m0 + row) * K + k0 + kcl * 8], &lA[rowg * 64]);
      load_lds16(&Bb[(size_t)(n0 + row) * K + k0 + kcl * 8], &lB[rowg * 64]);
    }
    __syncthreads();
    #pragma unroll
    for (int kk = 0; kk < 2; kk++) {
      bf16x8 af[4], bfr[4];
      #pragma unroll
      for (int mt = 0; mt < 4; mt++) {
        int row = wm * 64 + mt * 16 + ln15;
        int pc  = (kk * 4 + q4) ^ (row & 7);
        af[mt] = *(const bf16x8*)&lA[row * 64 + pc * 8];
      }
      #pragma unroll
      for (int nt = 0; nt < 4; nt++) {
        int row = wn * 64 + nt * 16 + ln15;
        int pc  = (kk * 4 + q4) ^ (row & 7);
        bfr[nt] = *(const bf16x8*)&lB[row * 64 + pc * 8];
      }
      #pragma unroll
      for (int mt = 0; mt < 4; mt++)
        #pragma unroll
        for (int nt = 0; nt < 4; nt++)
          acc[mt][nt] = __builtin_amdgcn_mfma_f32_16x16x32_bf16(
              af[mt], bfr[nt], acc[mt][nt], 0, 0, 0);
    }
    __syncthreads();
  }

  if (MODE == 0) {
    unsigned short* Sb = (unsigned short*)Cout + (size_t)zz * 1024 * 1024;
    #pragma unroll
    for (int mt = 0; mt < 4; mt++) {
      #pragma unroll
      for (int nt = 0; nt < 4; nt++) {
        int col = n0 + wn * 64 + nt * 16 + ln15;
        #pragma unroll
        for (int rg = 0; rg < 4; rg++) {
          int rowi = m0 + wm * 64 + mt * 16 + q4 * 4 + rg;
          Sb[(size_t)rowi * 1024 + col] = (unsigned short)f2bf(acc[mt][nt][rg] * scale);
        }
      }
    }
  } else {
    float* Ob = (float*)Cout;
    #pragma unroll
    for (int mt = 0; mt < 4; mt++) {
      #pragma unroll
      for (int nt = 0; nt < 4; nt++) {
        int l  = n0 + wn * 64 + nt * 16 + ln15;
        int i1 = l >> 5, j1 = l & 31;
        #pragma unroll
        for (int rg = 0; rg < 4; rg++) {
          int rloc = wm * 64 + mt * 16 + q4 * 4 + rg;
          int dp = m0 + rloc;
          int c  = dp & 31;
          int j0 = (dp >> 5) & 7;
          int i0 = dp >> 8;
          int h = i0 * 32 + i1;
          int w = j0 * 32 + j1;
          if (h < 252 && w < 252)
            Ob[(((size_t)zz * 32 + c) * 252 + h) * 252 + w] =
                acc[mt][nt][rg] * svb[rloc];
        }
      }
    }
  }
}

// ---------------------------------------------------------------------------
// Kernel 5: row softmax over S (bf16, in place -> P). Block per row (b,l).
// ---------------------------------------------------------------------------
__global__ void softmax_kernel(unsigned short* __restrict__ S) {
  unsigned short* row = S + (size_t)blockIdx.x * 1024;
  int tid  = threadIdx.x;
  int lane = tid & 63;
  int wid  = tid >> 6;

  uint2 u = *(const uint2*)&row[tid * 4];
  float x0 = bf2f(u.x & 0xFFFF);
  float x1 = bf2f(u.x >> 16);
  float x2 = bf2f(u.y & 0xFFFF);
  float x3 = bf2f(u.y >> 16);

  __shared__ float red[8];
  float mx = fmaxf(fmaxf(x0, x1), fmaxf(x2, x3));
  #pragma unroll
  for (int off = 32; off > 0; off >>= 1) mx = fmaxf(mx, __shfl_down(mx, off));
  if (lane == 0) red[wid] = mx;
  __syncthreads();
  if (tid == 0)
    red[4] = fmaxf(fmaxf(red[0], red[1]), fmaxf(red[2], red[3]));
  __syncthreads();
  float bm = red[4];

  float e0 = __expf(x0 - bm), e1 = __expf(x1 - bm);
  float e2 = __expf(x2 - bm), e3 = __expf(x3 - bm);
  float s = e0 + e1 + e2 + e3;
  #pragma unroll
  for (int off = 32; off > 0; off >>= 1) s += __shfl_down(s, off);
  if (lane == 0) red[wid] = s;
  __syncthreads();
  if (tid == 0) red[5] = 1.0f / (red[0] + red[1] + red[2] + red[3]);
  __syncthreads();
  float inv = red[5];

  unsigned int o0 = f2bf(e0 * inv) | (f2bf(e1 * inv) << 16);
  unsigned int o1 = f2bf(e2 * inv) | (f2bf(e3 * inv) << 16);
  uint2 o; o.x = o0; o.y = o1;
  *(uint2*)&row[tid * 4] = o;
}

// ---------------------------------------------------------------------------
extern "C" void kernel_launch(void* const* d_in, const int* in_sizes, int n_in,
                              void* d_out, int out_size, void* d_ws, size_t ws_size,
                              hipStream_t stream) {
  const float* q = (const float*)d_in[0];
  const float* k = (const float*)d_in[1];
  const float* v = (const float*)d_in[2];
  float* out = (float*)d_out;

  char* ws = (char*)d_ws;
  float* sv = (float*)ws;                                       // 8*2048*4 = 64 KB
  unsigned short* Qh = (unsigned short*)(ws + 196608);          // 32 MB
  unsigned short* Kh = Qh + (size_t)8 * 1024 * 2048;            // 32 MB
  unsigned short* Vt = Kh + (size_t)8 * 1024 * 2048;            // 32 MB
  unsigned short* S  = Vt + (size_t)8 * 2048 * 1024;            // 16 MB

  const float SIM_SCALE = 0.02209708691207961f;  // 2048^-0.5

  hipMemsetAsync(sv, 0, (size_t)8 * 2048 * sizeof(float), stream);
  pack_qk_fused<<<1024, 512, 0, stream>>>(q, k, Qh, Kh);
  pack_v_kernel<<<2048, 256, 0, stream>>>(v, Vt, sv);
  gemm_nt<0><<<512, 256, 0, stream>>>(
      Qh, Kh, 2048, 1024 * 2048, 1024 * 2048, (void*)S, SIM_SCALE, nullptr);
  softmax_kernel<<<8192, 256, 0, stream>>>(S);
  gemm_nt<1><<<1024, 256, 0, stream>>>(
      Vt, S, 1024, 2048 * 1024, 1024 * 1024, (void*)out, 1.0f, sv);
}

// Round 17
// 350.142 us; speedup vs baseline: 1.1568x; 1.0176x over previous
//
#include <hip/hip_runtime.h>
#include <cstdint>
#include <cstddef>

// ---------------------------------------------------------------------------
// cross_attention: b=8, c=32, 252x252, ws=8 -> padded 256x256.
// tokens l=(i1,j1) in 32x32, features d'=(i0*256 + j0*32 + c) in 2048.
// Pipeline (R15, resubmitted x2 after container-failure): pack_qk_fused v6
//   (per-window write-once, 512 thr) -> pack_v (raw bf16 Vt + fused svsum
//   atomics) ->
//   gemm1: expS = exp(Qh Kh^T * 2048^-0.5) stored bf16 + per-row sums via
//     shfl+atomicAdd (NO max-subtraction: dim-1 norm bounds |S| <= ~0.05,
//     exp overflow impossible — softmax_kernel ELIMINATED, -32 MB RT) ->
//   gemm2: Ot = (rsqrt(svsum).*Vt) expS^T, epilogue multiplies 1/rowsum[l].
// Numerics audit (R15): bf16-storing exp(x)~1+x (x std ~1e-3) quantizes at
//   2^-9 abs -> P error ~1.9e-6/elem == old pipeline's bf16-P storage error
//   (P*2^-9). Same error profile as the passing chain; absmax should hold.
// R16 audit: no kernel-side crash vector found (shfl_xor width-16 legal,
//   atomics bounded, graph-capture-safe calls only) — resubmitting
//   byte-identical to disambiguate infra flake vs kernel-triggered failure.
// ---------------------------------------------------------------------------

typedef __bf16 bf16x8 __attribute__((ext_vector_type(8)));
typedef float  f32x4  __attribute__((ext_vector_type(4)));

__device__ __forceinline__ unsigned int f2bf(float f) {
  unsigned int u = __builtin_bit_cast(unsigned int, f);
  u += 0x7FFFu + ((u >> 16) & 1u);   // round-to-nearest-even
  return u >> 16;
}
__device__ __forceinline__ float bf2f(unsigned int h) {
  return __builtin_bit_cast(float, h << 16);
}

__device__ __forceinline__ void load_lds16(const void* g, void* l) {
  __builtin_amdgcn_global_load_lds(
      (const __attribute__((address_space(1))) void*)g,
      (__attribute__((address_space(3))) void*)l, 16, 0, 0);
}

// ---------------------------------------------------------------------------
// Kernel 1 (v6): fused norm+pack for Q,K, per-window LDS tile, 512 threads.
// (unchanged from R14 — measured: 191 MB, ~75 us, occ 36%)
// ---------------------------------------------------------------------------
__global__ __launch_bounds__(512)
void pack_qk_fused(const float* __restrict__ q, const float* __restrict__ k,
                   unsigned short* __restrict__ Qh,
                   unsigned short* __restrict__ Kh) {
  int bx  = blockIdx.x;          // grid 1024
  int t   = bx >> 9;             // 0..1
  int b   = (bx >> 6) & 7;
  int i0  = (bx >> 3) & 7;
  int j0  = bx & 7;
  const float* xb = (t ? k : q) + (size_t)b * 32 * 63504;

  __shared__ unsigned short tile[1024 * 36];   // 72 KB -> 2 blocks/CU
  __shared__ float red[512];
  __shared__ float sclt[32];

  int tid = threadIdx.x;
  int ch  = tid & 7;               // w-chunk (4 floats)
  int i1h = (tid >> 3) & 1;        // row half
  int c   = tid >> 4;              // channel 0..31

  int wbase = j0 * 32 + ch * 4;
  float we[4];
  #pragma unroll
  for (int e = 0; e < 4; e++) {
    int w = wbase + e;
    we[e] = (w >= 252) ? 0.f : (((unsigned)(w - 247) <= 3u) ? 2.f : 1.f);
  }
  bool tail = (wbase == 252);      // only j0==7, ch==7

  float pa = 0.f;
  unsigned short* X = (t ? Kh : Qh) + (size_t)b * 1024 * 2048;
  const float* csrc = xb + (size_t)c * 63504;

  // ---- Phase A: stage + squares (no barriers; 16 independent loads) ----
  #pragma unroll 4
  for (int r = 0; r < 16; r++) {
    int i1 = i1h * 16 + r;
    int h  = i0 * 32 + i1;
    int hs = (h < 252) ? h : 502 - h;
    float rw = (h >= 252) ? 0.f : (((unsigned)(h - 247) <= 3u) ? 2.f : 1.f);
    const float* rowp = csrc + (size_t)hs * 252;

    float4 vv;
    if (!tail) {
      vv = *(const float4*)&rowp[wbase];
    } else {  // w 252..255 mirror to 250,249,248,247
      vv.x = rowp[250]; vv.y = rowp[249]; vv.z = rowp[248]; vv.w = rowp[247];
    }
    pa += rw * (we[0] * vv.x * vv.x + we[1] * vv.y * vv.y +
                we[2] * vv.z * vv.z + we[3] * vv.w * vv.w);
    int lbase = i1 * 32 + ch * 4;          // token = i1*32 + j1
    unsigned short* tp = &tile[(size_t)lbase * 36 + c];
    tp[0]   = (unsigned short)f2bf(vv.x);
    tp[36]  = (unsigned short)f2bf(vv.y);
    tp[72]  = (unsigned short)f2bf(vv.z);
    tp[108] = (unsigned short)f2bf(vv.w);
  }
  __syncthreads();

  // ---- Phase B: reduce 16 partials per channel -> 32 scales ----
  red[tid] = pa;
  __syncthreads();
  if (tid < 32) {
    float s = 0.f;
    #pragma unroll
    for (int u = 0; u < 16; u++) s += red[tid * 16 + u];
    sclt[tid] = 1.f / fmaxf(sqrtf(s), 1e-12f);
  }
  __syncthreads();

  // ---- Phase C': scaled write-out, each output byte written once ----
  {
    int qd   = tid & 7;            // c quad: c = qd*4 .. qd*4+3
    int lidx = tid >> 3;           // 0..63
    float sc[4];
    #pragma unroll
    for (int m = 0; m < 4; m++) sc[m] = sclt[qd * 4 + m];
    unsigned short* Xb = &X[i0 * 256 + j0 * 32 + qd * 4];
    #pragma unroll 4
    for (int it = 0; it < 16; it++) {
      int l = it * 64 + lidx;
      uint2 u = *(const uint2*)&tile[(size_t)l * 36 + qd * 4];
      uint2 o2;
      o2.x = f2bf(bf2f(u.x & 0xFFFF) * sc[0]) |
             (f2bf(bf2f(u.x >> 16)   * sc[1]) << 16);
      o2.y = f2bf(bf2f(u.y & 0xFFFF) * sc[2]) |
             (f2bf(bf2f(u.y >> 16)   * sc[3]) << 16);
      *(uint2*)&Xb[(size_t)l * 2048] = o2;
    }
  }
}

// ---------------------------------------------------------------------------
// Kernel 2: pack V to bf16 Vt[d'][l] — RAW (scale folded into gemm2), no LDS.
// Fused: sum-of-squares per (b, d') row accumulated into svsum via 4-lane
// shfl reduce + one atomicAdd per (c, j0) per block. svsum zeroed via
// hipMemsetAsync before launch.
// ---------------------------------------------------------------------------
__global__ void pack_v_kernel(const float* __restrict__ v,
                              unsigned short* __restrict__ Vt,
                              float* __restrict__ svsum) {
  int bx = blockIdx.x;
  int b  = bx >> 8;
  int i0 = (bx >> 5) & 7;
  int i1 = bx & 31;
  int h  = i0 * 32 + i1;
  int hs = (h < 252) ? h : 502 - h;
  const float* src = v + (size_t)b * 32 * 63504 + (size_t)hs * 252;
  unsigned short* dst = Vt + (size_t)b * 2048 * 1024
                           + (size_t)(i0 * 256) * 1024 + i1 * 32;

  int tid = threadIdx.x;
  int j1c = tid & 3;
  int c   = (tid >> 2) & 31;
  int j0g = tid >> 7;          // 0..1
  const float* s = src + (size_t)c * 63504;

  float psum[4];

  #pragma unroll
  for (int jj = 0; jj < 4; jj++) {
    int j0 = j0g * 4 + jj;
    int w0 = j0 * 32 + j1c * 8;
    float f0, f1, f2, f3, f4, f5, f6, f7;
    if (w0 + 8 <= 252) {
      float4 a = *(const float4*)&s[w0];
      float4 bq = *(const float4*)&s[w0 + 4];
      f0 = a.x; f1 = a.y; f2 = a.z; f3 = a.w;
      f4 = bq.x; f5 = bq.y; f6 = bq.z; f7 = bq.w;
    } else {  // w0==248: cols 248..255 -> 248,249,250,251,250,249,248,247
      float4 a = *(const float4*)&s[244];
      float4 bq = *(const float4*)&s[248];
      f0 = bq.x; f1 = bq.y; f2 = bq.z; f3 = bq.w;
      f4 = bq.z; f5 = bq.y; f6 = bq.x; f7 = a.w;
    }
    psum[jj] = f0*f0 + f1*f1 + f2*f2 + f3*f3 + f4*f4 + f5*f5 + f6*f6 + f7*f7;
    uint4 o;
    o.x = f2bf(f0) | (f2bf(f1) << 16);
    o.y = f2bf(f2) | (f2bf(f3) << 16);
    o.z = f2bf(f4) | (f2bf(f5) << 16);
    o.w = f2bf(f6) | (f2bf(f7) << 16);
    *(uint4*)&dst[(size_t)(j0 * 32 + c) * 1024 + j1c * 8] = o;
  }

  #pragma unroll
  for (int jj = 0; jj < 4; jj++) {
    float ssum = psum[jj];
    ssum += __shfl_down(ssum, 2, 4);
    ssum += __shfl_down(ssum, 1, 4);
    if (j1c == 0) {
      int j0 = j0g * 4 + jj;
      atomicAdd(&svsum[(size_t)b * 2048 + i0 * 256 + j0 * 32 + c], ssum);
    }
  }
}

// ---------------------------------------------------------------------------
// GEMM NT: C[M][N] = A[M][K] * B[N][K]^T, bf16 in, fp32 acc.
// 1D grid, decode: b = flat&7 (XCD affinity), m, n of the remainder.
// MODE 0: store bf16 exp(acc*scale) and atomicAdd per-row partial sums to
//   rs[zz*1024 + row] (no max-subtraction: |S| <= ~0.05 by dim-1 norm).
// MODE 1: acc *= rsqrt(svsum[row]) * (1/rs[col]), scatter fp32 + crop.
// ---------------------------------------------------------------------------
template <int MODE>
__global__ __launch_bounds__(256, 4)
void gemm_nt(const unsigned short* __restrict__ A,
             const unsigned short* __restrict__ B,
             int K, int Asb, int Bsb, void* __restrict__ Cout, float scale,
             const float* __restrict__ sv, float* __restrict__ rs) {
  __shared__ unsigned short lA[128 * 64];
  __shared__ unsigned short lB[128 * 64];
  __shared__ float svb[(MODE == 1) ? 128 : 1];
  __shared__ float rsb[(MODE == 1) ? 128 : 1];

  const int flat = blockIdx.x;
  const int zz   = flat & 7;
  const int rr   = flat >> 3;
  const int my   = rr >> 3;
  const int nx   = rr & 7;

  const int tid  = threadIdx.x;
  const int lane = tid & 63;
  const int wave = tid >> 6;
  const int ln15 = lane & 15;
  const int q4   = lane >> 4;
  const int wm   = wave >> 1;
  const int wn   = wave & 1;
  const int m0   = my * 128;
  const int n0   = nx * 128;
  const unsigned short* Ab = A + (size_t)zz * Asb;
  const unsigned short* Bb = B + (size_t)zz * Bsb;

  if (MODE == 1 && tid < 128) {
    svb[tid] = 1.f / fmaxf(sqrtf(sv[(size_t)zz * 2048 + m0 + tid]), 1e-12f);
    rsb[tid] = 1.f / rs[(size_t)zz * 1024 + n0 + tid];
  }

  const int srow = lane >> 3;
  const int kcp  = lane & 7;
  const int kcl  = kcp ^ srow;      // xor-swizzled source chunk

  f32x4 acc[4][4] = {};

  for (int k0 = 0; k0 < K; k0 += 64) {
    #pragma unroll
    for (int r = 0; r < 4; r++) {
      int rowg = wave * 32 + r * 8;
      int row  = rowg + srow;
      load_lds16(&Ab[(size_t)(m0 + row) * K + k0 + kcl * 8], &lA[rowg * 64]);
      load_lds16(&Bb[(size_t)(n0 + row) * K + k0 + kcl * 8], &lB[rowg * 64]);
    }
    __syncthreads();
    #pragma unroll
    for (int kk = 0; kk < 2; kk++) {
      bf16x8 af[4], bfr[4];
      #pragma unroll
      for (int mt = 0; mt < 4; mt++) {
        int row = wm * 64 + mt * 16 + ln15;
        int pc  = (kk * 4 + q4) ^ (row & 7);
        af[mt] = *(const bf16x8*)&lA[row * 64 + pc * 8];
      }
      #pragma unroll
      for (int nt = 0; nt < 4; nt++) {
        int row = wn * 64 + nt * 16 + ln15;
        int pc  = (kk * 4 + q4) ^ (row & 7);
        bfr[nt] = *(const bf16x8*)&lB[row * 64 + pc * 8];
      }
      #pragma unroll
      for (int mt = 0; mt < 4; mt++)
        #pragma unroll
        for (int nt = 0; nt < 4; nt++)
          acc[mt][nt] = __builtin_amdgcn_mfma_f32_16x16x32_bf16(
              af[mt], bfr[nt], acc[mt][nt], 0, 0, 0);
    }
    __syncthreads();
  }

  if (MODE == 0) {
    unsigned short* Sb = (unsigned short*)Cout + (size_t)zz * 1024 * 1024;
    #pragma unroll
    for (int mt = 0; mt < 4; mt++) {
      #pragma unroll
      for (int rg = 0; rg < 4; rg++) {
        int rowi = m0 + wm * 64 + mt * 16 + q4 * 4 + rg;
        float s = 0.f;
        #pragma unroll
        for (int nt = 0; nt < 4; nt++) {
          float e = __expf(acc[mt][nt][rg] * scale);
          s += e;
          int col = n0 + wn * 64 + nt * 16 + ln15;
          Sb[(size_t)rowi * 1024 + col] = (unsigned short)f2bf(e);
        }
        // sum over the 16 ln15 lanes (same rowi) -> 64-col partial
        s += __shfl_xor(s, 1, 16);
        s += __shfl_xor(s, 2, 16);
        s += __shfl_xor(s, 4, 16);
        s += __shfl_xor(s, 8, 16);
        if (ln15 == 0)
          atomicAdd(&rs[(size_t)zz * 1024 + rowi], s);
      }
    }
  } else {
    float* Ob = (float*)Cout;
    #pragma unroll
    for (int mt = 0; mt < 4; mt++) {
      #pragma unroll
      for (int nt = 0; nt < 4; nt++) {
        int lcol = wn * 64 + nt * 16 + ln15;
        int l  = n0 + lcol;
        int i1 = l >> 5, j1 = l & 31;
        float rv = rsb[lcol];
        #pragma unroll
        for (int rg = 0; rg < 4; rg++) {
          int rloc = wm * 64 + mt * 16 + q4 * 4 + rg;
          int dp = m0 + rloc;
          int c  = dp & 31;
          int j0 = (dp >> 5) & 7;
          int i0 = dp >> 8;
          int h = i0 * 32 + i1;
          int w = j0 * 32 + j1;
          if (h < 252 && w < 252)
            Ob[(((size_t)zz * 32 + c) * 252 + h) * 252 + w] =
                acc[mt][nt][rg] * svb[rloc] * rv;
        }
      }
    }
  }
}

// ---------------------------------------------------------------------------
extern "C" void kernel_launch(void* const* d_in, const int* in_sizes, int n_in,
                              void* d_out, int out_size, void* d_ws, size_t ws_size,
                              hipStream_t stream) {
  const float* q = (const float*)d_in[0];
  const float* k = (const float*)d_in[1];
  const float* v = (const float*)d_in[2];
  float* out = (float*)d_out;

  char* ws = (char*)d_ws;
  float* sv = (float*)ws;                                       // 8*2048*4 = 64 KB
  float* rsum = (float*)(ws + 65536);                           // 8*1024*4 = 32 KB
  unsigned short* Qh = (unsigned short*)(ws + 196608);          // 32 MB
  unsigned short* Kh = Qh + (size_t)8 * 1024 * 2048;            // 32 MB
  unsigned short* Vt = Kh + (size_t)8 * 1024 * 2048;            // 32 MB
  unsigned short* S  = Vt + (size_t)8 * 2048 * 1024;            // 16 MB

  const float SIM_SCALE = 0.02209708691207961f;  // 2048^-0.5

  hipMemsetAsync(sv, 0, 98304, stream);   // zero sv (64 KB) + rsum (32 KB)
  pack_qk_fused<<<1024, 512, 0, stream>>>(q, k, Qh, Kh);
  pack_v_kernel<<<2048, 256, 0, stream>>>(v, Vt, sv);
  gemm_nt<0><<<512, 256, 0, stream>>>(
      Qh, Kh, 2048, 1024 * 2048, 1024 * 2048, (void*)S, SIM_SCALE, nullptr,
      rsum);
  gemm_nt<1><<<1024, 256, 0, stream>>>(
      Vt, S, 1024, 2048 * 1024, 1024 * 1024, (void*)out, 1.0f, sv, rsum);
}

// Round 18
// 348.787 us; speedup vs baseline: 1.1613x; 1.0039x over previous
//
#include <hip/hip_runtime.h>
#include <cstdint>
#include <cstddef>

// ---------------------------------------------------------------------------
// cross_attention: b=8, c=32, 252x252, ws=8 -> padded 256x256.
// tokens l=(i1,j1) in 32x32, features d'=(i0*256 + j0*32 + c) in 2048.
// Pipeline (R18): pack_qk v6 SPLIT INTO TWO DISPATCHES (t as arg) — purely
//   diagnostic: each half ~37 us < gemm/pack_v durations, so the top-5
//   table finally surfaces gemm1/gemm2/pack_v counters (they have never
//   been measured; ~100 us of the 350 total is unattributed).
//   -> pack_v (raw bf16 Vt + fused svsum atomics) ->
//   gemm1: expS = exp(Qh Kh^T * 2048^-0.5) bf16 + rowsums via shfl+atomic
//     (no max-subtraction; verified R17, absmax 1.5e-5) ->
//   gemm2: Ot = (rsqrt(svsum).*Vt) expS^T, epilogue * 1/rowsum[l].
// R17: 350.1 us. pack_qk ~73 (plateau 2.6-2.7 TB/s, 191 MB); softmax
// eliminated (-6 us vs predicted -20; falsifier fired -> measure gemms
// before rebuilding them).
// ---------------------------------------------------------------------------

typedef __bf16 bf16x8 __attribute__((ext_vector_type(8)));
typedef float  f32x4  __attribute__((ext_vector_type(4)));

__device__ __forceinline__ unsigned int f2bf(float f) {
  unsigned int u = __builtin_bit_cast(unsigned int, f);
  u += 0x7FFFu + ((u >> 16) & 1u);   // round-to-nearest-even
  return u >> 16;
}
__device__ __forceinline__ float bf2f(unsigned int h) {
  return __builtin_bit_cast(float, h << 16);
}

__device__ __forceinline__ void load_lds16(const void* g, void* l) {
  __builtin_amdgcn_global_load_lds(
      (const __attribute__((address_space(1))) void*)g,
      (__attribute__((address_space(3))) void*)l, 16, 0, 0);
}

// ---------------------------------------------------------------------------
// Kernel 1 (v6-split): fused norm+pack for Q or K (tsel), per-window LDS
// tile, 512 threads. Grid 512 = (b, i0, j0). Structure identical to the
// R14/R17-verified v6; only the t decode moved to an argument.
// ---------------------------------------------------------------------------
__global__ __launch_bounds__(512)
void pack_qk_fused(const float* __restrict__ q, const float* __restrict__ k,
                   unsigned short* __restrict__ Qh,
                   unsigned short* __restrict__ Kh, int tsel) {
  int bx  = blockIdx.x;          // grid 512
  int b   = (bx >> 6) & 7;
  int i0  = (bx >> 3) & 7;
  int j0  = bx & 7;
  const float* xb = (tsel ? k : q) + (size_t)b * 32 * 63504;

  __shared__ unsigned short tile[1024 * 36];   // 72 KB -> 2 blocks/CU
  __shared__ float red[512];
  __shared__ float sclt[32];

  int tid = threadIdx.x;
  int ch  = tid & 7;               // w-chunk (4 floats)
  int i1h = (tid >> 3) & 1;        // row half
  int c   = tid >> 4;              // channel 0..31

  int wbase = j0 * 32 + ch * 4;
  float we[4];
  #pragma unroll
  for (int e = 0; e < 4; e++) {
    int w = wbase + e;
    we[e] = (w >= 252) ? 0.f : (((unsigned)(w - 247) <= 3u) ? 2.f : 1.f);
  }
  bool tail = (wbase == 252);      // only j0==7, ch==7

  float pa = 0.f;
  unsigned short* X = (tsel ? Kh : Qh) + (size_t)b * 1024 * 2048;
  const float* csrc = xb + (size_t)c * 63504;

  // ---- Phase A: stage + squares (no barriers; 16 independent loads) ----
  #pragma unroll 4
  for (int r = 0; r < 16; r++) {
    int i1 = i1h * 16 + r;
    int h  = i0 * 32 + i1;
    int hs = (h < 252) ? h : 502 - h;
    float rw = (h >= 252) ? 0.f : (((unsigned)(h - 247) <= 3u) ? 2.f : 1.f);
    const float* rowp = csrc + (size_t)hs * 252;

    float4 vv;
    if (!tail) {
      vv = *(const float4*)&rowp[wbase];
    } else {  // w 252..255 mirror to 250,249,248,247
      vv.x = rowp[250]; vv.y = rowp[249]; vv.z = rowp[248]; vv.w = rowp[247];
    }
    pa += rw * (we[0] * vv.x * vv.x + we[1] * vv.y * vv.y +
                we[2] * vv.z * vv.z + we[3] * vv.w * vv.w);
    int lbase = i1 * 32 + ch * 4;          // token = i1*32 + j1
    unsigned short* tp = &tile[(size_t)lbase * 36 + c];
    tp[0]   = (unsigned short)f2bf(vv.x);
    tp[36]  = (unsigned short)f2bf(vv.y);
    tp[72]  = (unsigned short)f2bf(vv.z);
    tp[108] = (unsigned short)f2bf(vv.w);
  }
  __syncthreads();

  // ---- Phase B: reduce 16 partials per channel -> 32 scales ----
  red[tid] = pa;
  __syncthreads();
  if (tid < 32) {
    float s = 0.f;
    #pragma unroll
    for (int u = 0; u < 16; u++) s += red[tid * 16 + u];
    sclt[tid] = 1.f / fmaxf(sqrtf(s), 1e-12f);
  }
  __syncthreads();

  // ---- Phase C': scaled write-out, each output byte written once ----
  {
    int qd   = tid & 7;            // c quad: c = qd*4 .. qd*4+3
    int lidx = tid >> 3;           // 0..63
    float sc[4];
    #pragma unroll
    for (int m = 0; m < 4; m++) sc[m] = sclt[qd * 4 + m];
    unsigned short* Xb = &X[i0 * 256 + j0 * 32 + qd * 4];
    #pragma unroll 4
    for (int it = 0; it < 16; it++) {
      int l = it * 64 + lidx;
      uint2 u = *(const uint2*)&tile[(size_t)l * 36 + qd * 4];
      uint2 o2;
      o2.x = f2bf(bf2f(u.x & 0xFFFF) * sc[0]) |
             (f2bf(bf2f(u.x >> 16)   * sc[1]) << 16);
      o2.y = f2bf(bf2f(u.y & 0xFFFF) * sc[2]) |
             (f2bf(bf2f(u.y >> 16)   * sc[3]) << 16);
      *(uint2*)&Xb[(size_t)l * 2048] = o2;
    }
  }
}

// ---------------------------------------------------------------------------
// Kernel 2: pack V to bf16 Vt[d'][l] — RAW (scale folded into gemm2), no LDS.
// Fused: sum-of-squares per (b, d') row accumulated into svsum via 4-lane
// shfl reduce + one atomicAdd per (c, j0) per block. svsum zeroed via
// hipMemsetAsync before launch.
// ---------------------------------------------------------------------------
__global__ void pack_v_kernel(const float* __restrict__ v,
                              unsigned short* __restrict__ Vt,
                              float* __restrict__ svsum) {
  int bx = blockIdx.x;
  int b  = bx >> 8;
  int i0 = (bx >> 5) & 7;
  int i1 = bx & 31;
  int h  = i0 * 32 + i1;
  int hs = (h < 252) ? h : 502 - h;
  const float* src = v + (size_t)b * 32 * 63504 + (size_t)hs * 252;
  unsigned short* dst = Vt + (size_t)b * 2048 * 1024
                           + (size_t)(i0 * 256) * 1024 + i1 * 32;

  int tid = threadIdx.x;
  int j1c = tid & 3;
  int c   = (tid >> 2) & 31;
  int j0g = tid >> 7;          // 0..1
  const float* s = src + (size_t)c * 63504;

  float psum[4];

  #pragma unroll
  for (int jj = 0; jj < 4; jj++) {
    int j0 = j0g * 4 + jj;
    int w0 = j0 * 32 + j1c * 8;
    float f0, f1, f2, f3, f4, f5, f6, f7;
    if (w0 + 8 <= 252) {
      float4 a = *(const float4*)&s[w0];
      float4 bq = *(const float4*)&s[w0 + 4];
      f0 = a.x; f1 = a.y; f2 = a.z; f3 = a.w;
      f4 = bq.x; f5 = bq.y; f6 = bq.z; f7 = bq.w;
    } else {  // w0==248: cols 248..255 -> 248,249,250,251,250,249,248,247
      float4 a = *(const float4*)&s[244];
      float4 bq = *(const float4*)&s[248];
      f0 = bq.x; f1 = bq.y; f2 = bq.z; f3 = bq.w;
      f4 = bq.z; f5 = bq.y; f6 = bq.x; f7 = a.w;
    }
    psum[jj] = f0*f0 + f1*f1 + f2*f2 + f3*f3 + f4*f4 + f5*f5 + f6*f6 + f7*f7;
    uint4 o;
    o.x = f2bf(f0) | (f2bf(f1) << 16);
    o.y = f2bf(f2) | (f2bf(f3) << 16);
    o.z = f2bf(f4) | (f2bf(f5) << 16);
    o.w = f2bf(f6) | (f2bf(f7) << 16);
    *(uint4*)&dst[(size_t)(j0 * 32 + c) * 1024 + j1c * 8] = o;
  }

  #pragma unroll
  for (int jj = 0; jj < 4; jj++) {
    float ssum = psum[jj];
    ssum += __shfl_down(ssum, 2, 4);
    ssum += __shfl_down(ssum, 1, 4);
    if (j1c == 0) {
      int j0 = j0g * 4 + jj;
      atomicAdd(&svsum[(size_t)b * 2048 + i0 * 256 + j0 * 32 + c], ssum);
    }
  }
}

// ---------------------------------------------------------------------------
// GEMM NT: C[M][N] = A[M][K] * B[N][K]^T, bf16 in, fp32 acc.
// 1D grid, decode: b = flat&7 (XCD affinity), m, n of the remainder.
// MODE 0: store bf16 exp(acc*scale) and atomicAdd per-row partial sums to
//   rs[zz*1024 + row] (no max-subtraction: |S| <= ~0.05 by dim-1 norm).
// MODE 1: acc *= rsqrt(svsum[row]) * (1/rs[col]), scatter fp32 + crop.
// ---------------------------------------------------------------------------
template <int MODE>
__global__ __launch_bounds__(256, 4)
void gemm_nt(const unsigned short* __restrict__ A,
             const unsigned short* __restrict__ B,
             int K, int Asb, int Bsb, void* __restrict__ Cout, float scale,
             const float* __restrict__ sv, float* __restrict__ rs) {
  __shared__ unsigned short lA[128 * 64];
  __shared__ unsigned short lB[128 * 64];
  __shared__ float svb[(MODE == 1) ? 128 : 1];
  __shared__ float rsb[(MODE == 1) ? 128 : 1];

  const int flat = blockIdx.x;
  const int zz   = flat & 7;
  const int rr   = flat >> 3;
  const int my   = rr >> 3;
  const int nx   = rr & 7;

  const int tid  = threadIdx.x;
  const int lane = tid & 63;
  const int wave = tid >> 6;
  const int ln15 = lane & 15;
  const int q4   = lane >> 4;
  const int wm   = wave >> 1;
  const int wn   = wave & 1;
  const int m0   = my * 128;
  const int n0   = nx * 128;
  const unsigned short* Ab = A + (size_t)zz * Asb;
  const unsigned short* Bb = B + (size_t)zz * Bsb;

  if (MODE == 1 && tid < 128) {
    svb[tid] = 1.f / fmaxf(sqrtf(sv[(size_t)zz * 2048 + m0 + tid]), 1e-12f);
    rsb[tid] = 1.f / rs[(size_t)zz * 1024 + n0 + tid];
  }

  const int srow = lane >> 3;
  const int kcp  = lane & 7;
  const int kcl  = kcp ^ srow;      // xor-swizzled source chunk

  f32x4 acc[4][4] = {};

  for (int k0 = 0; k0 < K; k0 += 64) {
    #pragma unroll
    for (int r = 0; r < 4; r++) {
      int rowg = wave * 32 + r * 8;
      int row  = rowg + srow;
      load_lds16(&Ab[(size_t)(m0 + row) * K + k0 + kcl * 8], &lA[rowg * 64]);
      load_lds16(&Bb[(size_t)(n0 + row) * K + k0 + kcl * 8], &lB[rowg * 64]);
    }
    __syncthreads();
    #pragma unroll
    for (int kk = 0; kk < 2; kk++) {
      bf16x8 af[4], bfr[4];
      #pragma unroll
      for (int mt = 0; mt < 4; mt++) {
        int row = wm * 64 + mt * 16 + ln15;
        int pc  = (kk * 4 + q4) ^ (row & 7);
        af[mt] = *(const bf16x8*)&lA[row * 64 + pc * 8];
      }
      #pragma unroll
      for (int nt = 0; nt < 4; nt++) {
        int row = wn * 64 + nt * 16 + ln15;
        int pc  = (kk * 4 + q4) ^ (row & 7);
        bfr[nt] = *(const bf16x8*)&lB[row * 64 + pc * 8];
      }
      #pragma unroll
      for (int mt = 0; mt < 4; mt++)
        #pragma unroll
        for (int nt = 0; nt < 4; nt++)
          acc[mt][nt] = __builtin_amdgcn_mfma_f32_16x16x32_bf16(
              af[mt], bfr[nt], acc[mt][nt], 0, 0, 0);
    }
    __syncthreads();
  }

  if (MODE == 0) {
    unsigned short* Sb = (unsigned short*)Cout + (size_t)zz * 1024 * 1024;
    #pragma unroll
    for (int mt = 0; mt < 4; mt++) {
      #pragma unroll
      for (int rg = 0; rg < 4; rg++) {
        int rowi = m0 + wm * 64 + mt * 16 + q4 * 4 + rg;
        float s = 0.f;
        #pragma unroll
        for (int nt = 0; nt < 4; nt++) {
          float e = __expf(acc[mt][nt][rg] * scale);
          s += e;
          int col = n0 + wn * 64 + nt * 16 + ln15;
          Sb[(size_t)rowi * 1024 + col] = (unsigned short)f2bf(e);
        }
        // sum over the 16 ln15 lanes (same rowi) -> 64-col partial
        s += __shfl_xor(s, 1, 16);
        s += __shfl_xor(s, 2, 16);
        s += __shfl_xor(s, 4, 16);
        s += __shfl_xor(s, 8, 16);
        if (ln15 == 0)
          atomicAdd(&rs[(size_t)zz * 1024 + rowi], s);
      }
    }
  } else {
    float* Ob = (float*)Cout;
    #pragma unroll
    for (int mt = 0; mt < 4; mt++) {
      #pragma unroll
      for (int nt = 0; nt < 4; nt++) {
        int lcol = wn * 64 + nt * 16 + ln15;
        int l  = n0 + lcol;
        int i1 = l >> 5, j1 = l & 31;
        float rv = rsb[lcol];
        #pragma unroll
        for (int rg = 0; rg < 4; rg++) {
          int rloc = wm * 64 + mt * 16 + q4 * 4 + rg;
          int dp = m0 + rloc;
          int c  = dp & 31;
          int j0 = (dp >> 5) & 7;
          int i0 = dp >> 8;
          int h = i0 * 32 + i1;
          int w = j0 * 32 + j1;
          if (h < 252 && w < 252)
            Ob[(((size_t)zz * 32 + c) * 252 + h) * 252 + w] =
                acc[mt][nt][rg] * svb[rloc] * rv;
        }
      }
    }
  }
}

// ---------------------------------------------------------------------------
extern "C" void kernel_launch(void* const* d_in, const int* in_sizes, int n_in,
                              void* d_out, int out_size, void* d_ws, size_t ws_size,
                              hipStream_t stream) {
  const float* q = (const float*)d_in[0];
  const float* k = (const float*)d_in[1];
  const float* v = (const float*)d_in[2];
  float* out = (float*)d_out;

  char* ws = (char*)d_ws;
  float* sv = (float*)ws;                                       // 8*2048*4 = 64 KB
  float* rsum = (float*)(ws + 65536);                           // 8*1024*4 = 32 KB
  unsigned short* Qh = (unsigned short*)(ws + 196608);          // 32 MB
  unsigned short* Kh = Qh + (size_t)8 * 1024 * 2048;            // 32 MB
  unsigned short* Vt = Kh + (size_t)8 * 1024 * 2048;            // 32 MB
  unsigned short* S  = Vt + (size_t)8 * 2048 * 1024;            // 16 MB

  const float SIM_SCALE = 0.02209708691207961f;  // 2048^-0.5

  hipMemsetAsync(sv, 0, 98304, stream);   // zero sv (64 KB) + rsum (32 KB)
  pack_qk_fused<<<512, 512, 0, stream>>>(q, k, Qh, Kh, 0);
  pack_qk_fused<<<512, 512, 0, stream>>>(q, k, Qh, Kh, 1);
  pack_v_kernel<<<2048, 256, 0, stream>>>(v, Vt, sv);
  gemm_nt<0><<<512, 256, 0, stream>>>(
      Qh, Kh, 2048, 1024 * 2048, 1024 * 2048, (void*)S, SIM_SCALE, nullptr,
      rsum);
  gemm_nt<1><<<1024, 256, 0, stream>>>(
      Vt, S, 1024, 2048 * 1024, 1024 * 1024, (void*)out, 1.0f, sv, rsum);
}